// Round 3
// baseline (95040.973 us; speedup 1.0000x reference)
//
#include <hip/hip_runtime.h>

// LSTM T=4096, I=512, H=2048, 4H=8192, O=1 — ALL TENSORS FP32 (evidence: R2
// bf16 2-byte out-store read back as ~0 denormal => harness uses fp32 slots).
//
// Single persistent kernel: 256 WGs x 512 thr, 1 WG/CU. W_hh (64 MB fp32) and
// W_ih slices live in registers. Per step: grid-wide flag barrier, h broadcast
// via global ws buffer (double-buffered), LDS partial-sum reduction.

#define T_STEPS 4096
#define HID     2048
#define GATES   8192
#define KIN     512
#define NWG     256
#define NTHR    512

__global__ __launch_bounds__(NTHR, 2) void lstm_rec(
    const float* __restrict__ X,      // [T, 512]
    const float* __restrict__ Wih,    // [8192, 512]
    const float* __restrict__ Whh,    // [8192, 2048]
    const float* __restrict__ bih,    // [8192]
    const float* __restrict__ bhh,    // [8192]
    float* __restrict__ hbuf,         // [2, 2048] double buffer
    unsigned int* __restrict__ flags) // [256]
{
    const int wg = blockIdx.x;
    const int t  = threadIdx.x;
    const int kc = t & 127;   // k-chunk: h cols [kc*16,+16), x cols [kc*4,+4)
    const int rg = t >> 7;    // gate index 0..3 (i,f,g,o)
    const int j0 = wg * 8;    // this WG owns hidden units [j0, j0+8)

    // ---- one-time register-resident weights ----
    float whh[8][16];   // rows: gate rg, hidden j0+m (m<8); cols kc*16..+16
    float wih[8][4];    // same rows; x cols kc*4..+4
#pragma unroll
    for (int m = 0; m < 8; ++m) {
        const float* wr = Whh + (size_t)(rg * HID + j0 + m) * HID + kc * 16;
#pragma unroll
        for (int i = 0; i < 16; i += 4) {
            float4 v = *(const float4*)(wr + i);
            whh[m][i] = v.x; whh[m][i+1] = v.y; whh[m][i+2] = v.z; whh[m][i+3] = v.w;
        }
        float4 vx = *(const float4*)(Wih + (size_t)(rg * HID + j0 + m) * KIN + kc * 4);
        wih[m][0] = vx.x; wih[m][1] = vx.y; wih[m][2] = vx.z; wih[m][3] = vx.w;
    }

    // bias for the reducer threads (t<32: local row t = q*8+jj)
    float brow = 0.f;
    if (t < 32) {
        const int grow = (t >> 3) * HID + j0 + (t & 7);
        brow = bih[grow] + bhh[grow];
    }

    __shared__ float part[32 * 132];  // [row][kc padded to 132]
    __shared__ float gsum[32];

    float c_state = 0.f;  // threads t<8: cell state of hidden j0+t
    int dead = 0;

    for (int s = 0; s < T_STEPS; ++s) {
        const int pr = s & 1;

        // x-gate contribution (independent of h -> overlaps the poll)
        float4 x4 = *(const float4*)(X + (size_t)s * KIN + kc * 4);
        float acc[8];
#pragma unroll
        for (int m = 0; m < 8; ++m) {
            float a = wih[m][0] * x4.x;
            a = fmaf(wih[m][1], x4.y, a);
            a = fmaf(wih[m][2], x4.z, a);
            a = fmaf(wih[m][3], x4.w, a);
            acc[m] = a;
        }

        // wait until every WG has published h_s
        if (s > 0 && !dead) {
            const unsigned int target = 8u * (unsigned int)s;
            int iters = 0;
            for (;;) {
                int ok = 1;
                if (t < NWG)
                    ok = (__hip_atomic_load(&flags[t], __ATOMIC_RELAXED,
                                            __HIP_MEMORY_SCOPE_AGENT) >= target);
                if (__syncthreads_count(ok) == NTHR) break;
                if (++iters > 262144) { dead = 1; break; }
            }
            __builtin_amdgcn_fence(__ATOMIC_ACQUIRE, "agent");
        }

        // h-dot: 16 h values feed 8 rows each (128 FMAs)
        const float* hp = hbuf + (size_t)pr * HID + kc * 16;
        float4 h0 = ((const float4*)hp)[0];
        float4 h1 = ((const float4*)hp)[1];
        float4 h2 = ((const float4*)hp)[2];
        float4 h3 = ((const float4*)hp)[3];
#pragma unroll
        for (int m = 0; m < 8; ++m) {
            float a = acc[m];
            a = fmaf(whh[m][0],  h0.x, a); a = fmaf(whh[m][1],  h0.y, a);
            a = fmaf(whh[m][2],  h0.z, a); a = fmaf(whh[m][3],  h0.w, a);
            a = fmaf(whh[m][4],  h1.x, a); a = fmaf(whh[m][5],  h1.y, a);
            a = fmaf(whh[m][6],  h1.z, a); a = fmaf(whh[m][7],  h1.w, a);
            a = fmaf(whh[m][8],  h2.x, a); a = fmaf(whh[m][9],  h2.y, a);
            a = fmaf(whh[m][10], h2.z, a); a = fmaf(whh[m][11], h2.w, a);
            a = fmaf(whh[m][12], h3.x, a); a = fmaf(whh[m][13], h3.y, a);
            a = fmaf(whh[m][14], h3.z, a); a = fmaf(whh[m][15], h3.w, a);
            acc[m] = a;
        }

        // partials to LDS: part[row][kc], row = rg*8+m  (stride 132: no conflicts)
#pragma unroll
        for (int m = 0; m < 8; ++m)
            part[(rg * 8 + m) * 132 + kc] = acc[m];
        __syncthreads();

        // reduce each row's 128 partials (t<32), hand-reassociated
        if (t < 32) {
            const float4* p4 = (const float4*)(part + t * 132);
            float s0 = 0.f, s1 = 0.f, s2 = 0.f, s3 = 0.f;
#pragma unroll
            for (int i = 0; i < 32; ++i) {
                float4 v = p4[i];
                s0 += v.x; s1 += v.y; s2 += v.z; s3 += v.w;
            }
            gsum[t] = brow + ((s0 + s1) + (s2 + s3));
        }
        __syncthreads();

        // gate math + publish h_{s+1}
        if (t < 8) {
            const float ig = gsum[t];
            const float fg = gsum[8 + t];
            const float gg = gsum[16 + t];
            const float og = gsum[24 + t];
            const float i_s = 1.f / (1.f + __expf(-ig));
            const float f_s = 1.f / (1.f + __expf(-fg));
            const float g_t = tanhf(gg);
            const float o_s = 1.f / (1.f + __expf(-og));
            c_state = f_s * c_state + i_s * g_t;
            const float h = o_s * tanhf(c_state);
            __hip_atomic_store(&hbuf[(size_t)(pr ^ 1) * HID + j0 + t], h,
                               __ATOMIC_RELAXED, __HIP_MEMORY_SCOPE_AGENT);
            __hip_atomic_fetch_add(&flags[wg], 1u, __ATOMIC_RELEASE,
                                   __HIP_MEMORY_SCOPE_AGENT);
        }
        // next step's poll barrier (or the part[] barrier in dead mode) orders
        // gsum/part reuse; producers only advance flags after reading gsum.
    }
}

// out[0] = h_T . W_lin + b_lin   (fp32)
__global__ __launch_bounds__(256) void final_linear(const float* __restrict__ hbuf,
                                                    const float* __restrict__ Wlin,
                                                    const float* __restrict__ blin,
                                                    float* __restrict__ out) {
    __shared__ float red[4];
    const int t = threadIdx.x;
    float4 w0 = ((const float4*)Wlin)[t * 2];
    float4 w1 = ((const float4*)Wlin)[t * 2 + 1];
    float4 h0 = ((const float4*)hbuf)[t * 2];
    float4 h1 = ((const float4*)hbuf)[t * 2 + 1];
    float a = w0.x * h0.x;
    a = fmaf(w0.y, h0.y, a); a = fmaf(w0.z, h0.z, a); a = fmaf(w0.w, h0.w, a);
    a = fmaf(w1.x, h1.x, a); a = fmaf(w1.y, h1.y, a);
    a = fmaf(w1.z, h1.z, a); a = fmaf(w1.w, h1.w, a);
#pragma unroll
    for (int m = 1; m < 64; m <<= 1) a += __shfl_xor(a, m, 64);
    if ((t & 63) == 0) red[t >> 6] = a;
    __syncthreads();
    if (t == 0) out[0] = red[0] + red[1] + red[2] + red[3] + blin[0];
}

extern "C" void kernel_launch(void* const* d_in, const int* in_sizes, int n_in,
                              void* d_out, int out_size, void* d_ws, size_t ws_size,
                              hipStream_t stream) {
    const float* X    = (const float*)d_in[0];
    const float* Wih  = (const float*)d_in[1];
    const float* Whh  = (const float*)d_in[2];
    const float* bih  = (const float*)d_in[3];
    const float* bhh  = (const float*)d_in[4];
    const float* Wlin = (const float*)d_in[5];
    const float* blin = (const float*)d_in[6];
    float* out = (float*)d_out;

    char* ws = (char*)d_ws;
    float* hbuf           = (float*)ws;                    // 2*2048*4 = 16 KB
    unsigned int* flags   = (unsigned int*)(ws + 2 * HID * 4); // 1 KB

    // h_0 = 0, flags = 0 (ws is re-poisoned 0xAA before every call)
    (void)hipMemsetAsync(ws, 0, 2 * HID * 4 + NWG * 4, stream);

    // grid == CU count, 1 block/CU via __launch_bounds__(512,2): co-resident;
    // dead-valve in-kernel guarantees termination regardless.
    lstm_rec<<<dim3(NWG), dim3(NTHR), 0, stream>>>(X, Wih, Whh, bih, bhh, hbuf, flags);

    // step 4095 (pr=1) wrote h_T into parity 0
    final_linear<<<1, 256, 0, stream>>>(hbuf, Wlin, blin, out);
}

// Round 4
// 16630.450 us; speedup vs baseline: 5.7149x; 5.7149x over previous
//
#include <hip/hip_runtime.h>

// LSTM T=4096, I=512, H=2048, 4H=8192, O=1, fp32.
// R4: fence-free recurrence. h published as tagged u64 (value<<32 | step),
// double-buffered by parity; consumers poll only their own 16 words.
// No grid barrier, no fences, no atomic RMW. xg precomputed by fp32 GEMM.

#define T_STEPS 4096
#define HID     2048
#define GATES   8192
#define KIN     512
#define NWG     256
#define NTHR    512
#define XG_BYTES ((size_t)T_STEPS * GATES * 4)
#define HCOM_BYTES (2UL * HID * 8UL)

__device__ __forceinline__ float u2f(unsigned int u) {
    union { unsigned int u; float f; } x; x.u = u; return x.f;
}

// ---------------- xg = X @ Wih^T + (bih+bhh), fp32 tiled ----------------
// X[4096][512], Wih[8192][512] -> xg[4096][8192]
__global__ __launch_bounds__(256) void gemm_xg(const float* __restrict__ A,
                                               const float* __restrict__ B,
                                               const float* __restrict__ bih,
                                               const float* __restrict__ bhh,
                                               float* __restrict__ C) {
    __shared__ float As[32][68];   // [k][m]
    __shared__ float Bs[32][68];   // [k][n]
    const int t  = threadIdx.x;
    const int tx = t & 15, ty = t >> 4;
    const int m0 = blockIdx.y * 64, n0 = blockIdx.x * 64;
    const int sr = t >> 3, sc = (t & 7) * 4;

    float c[4][4] = {};
    for (int k0 = 0; k0 < KIN; k0 += 32) {
        float4 a0 = *(const float4*)(A + (size_t)(m0 + sr)      * KIN + k0 + sc);
        float4 a1 = *(const float4*)(A + (size_t)(m0 + sr + 32) * KIN + k0 + sc);
        float4 b0 = *(const float4*)(B + (size_t)(n0 + sr)      * KIN + k0 + sc);
        float4 b1 = *(const float4*)(B + (size_t)(n0 + sr + 32) * KIN + k0 + sc);
        __syncthreads();
        As[sc+0][sr] = a0.x; As[sc+1][sr] = a0.y; As[sc+2][sr] = a0.z; As[sc+3][sr] = a0.w;
        As[sc+0][sr+32] = a1.x; As[sc+1][sr+32] = a1.y; As[sc+2][sr+32] = a1.z; As[sc+3][sr+32] = a1.w;
        Bs[sc+0][sr] = b0.x; Bs[sc+1][sr] = b0.y; Bs[sc+2][sr] = b0.z; Bs[sc+3][sr] = b0.w;
        Bs[sc+0][sr+32] = b1.x; Bs[sc+1][sr+32] = b1.y; Bs[sc+2][sr+32] = b1.z; Bs[sc+3][sr+32] = b1.w;
        __syncthreads();
#pragma unroll
        for (int kk = 0; kk < 32; ++kk) {
            float4 av = *(const float4*)&As[kk][ty * 4];
            float4 bv = *(const float4*)&Bs[kk][tx * 4];
            c[0][0] = fmaf(av.x, bv.x, c[0][0]); c[0][1] = fmaf(av.x, bv.y, c[0][1]);
            c[0][2] = fmaf(av.x, bv.z, c[0][2]); c[0][3] = fmaf(av.x, bv.w, c[0][3]);
            c[1][0] = fmaf(av.y, bv.x, c[1][0]); c[1][1] = fmaf(av.y, bv.y, c[1][1]);
            c[1][2] = fmaf(av.y, bv.z, c[1][2]); c[1][3] = fmaf(av.y, bv.w, c[1][3]);
            c[2][0] = fmaf(av.z, bv.x, c[2][0]); c[2][1] = fmaf(av.z, bv.y, c[2][1]);
            c[2][2] = fmaf(av.z, bv.z, c[2][2]); c[2][3] = fmaf(av.z, bv.w, c[2][3]);
            c[3][0] = fmaf(av.w, bv.x, c[3][0]); c[3][1] = fmaf(av.w, bv.y, c[3][1]);
            c[3][2] = fmaf(av.w, bv.z, c[3][2]); c[3][3] = fmaf(av.w, bv.w, c[3][3]);
        }
    }
    const int col = n0 + tx * 4;
    float4 bias;
    bias.x = bih[col]   + bhh[col];
    bias.y = bih[col+1] + bhh[col+1];
    bias.z = bih[col+2] + bhh[col+2];
    bias.w = bih[col+3] + bhh[col+3];
#pragma unroll
    for (int i = 0; i < 4; ++i) {
        float4 o;
        o.x = c[i][0] + bias.x; o.y = c[i][1] + bias.y;
        o.z = c[i][2] + bias.z; o.w = c[i][3] + bias.w;
        *(float4*)(C + (size_t)(m0 + ty * 4 + i) * GATES + col) = o;
    }
}

// ---------------- persistent recurrence, tagged-h dataflow ----------------
// 256 WGs x 512 thr. WG owns hidden [8b,8b+8) = 32 gate rows.
// thread: kc=t&127 handles k in {g*128+kc}, rg=t>>7 gate, 8 rows each.
template<int USE_XG>
__global__ __launch_bounds__(NTHR, 2) void lstm_rec(
    const float* __restrict__ X,
    const float* __restrict__ Wih,
    const float* __restrict__ xg,
    const float* __restrict__ Whh,
    const float* __restrict__ bih,
    const float* __restrict__ bhh,
    unsigned long long* __restrict__ hcom)   // [2][2048] tagged
{
    const int t  = threadIdx.x;
    const int kc = t & 127;
    const int rg = t >> 7;
    const int j0 = blockIdx.x * 8;

    // register-resident W_hh slice: 8 rows x 16 cols (k = g*128+kc, coalesced)
    float whh[8][16];
#pragma unroll
    for (int m = 0; m < 8; ++m) {
        const float* wr = Whh + (size_t)(rg * HID + j0 + m) * HID + kc;
#pragma unroll
        for (int g = 0; g < 16; ++g) whh[m][g] = wr[g * 128];
    }
    float wih[8][4];
    if (!USE_XG) {
#pragma unroll
        for (int m = 0; m < 8; ++m) {
            float4 vx = *(const float4*)(Wih + (size_t)(rg * HID + j0 + m) * KIN + kc * 4);
            wih[m][0] = vx.x; wih[m][1] = vx.y; wih[m][2] = vx.z; wih[m][3] = vx.w;
        }
    }

    float brow = 0.f;
    if (t < 32) {
        const int grow = (t >> 3) * HID + j0 + (t & 7);
        brow = bih[grow] + bhh[grow];
    }

    __shared__ float part[32 * 132];
    __shared__ float gsum[32];
    float c_state = 0.f;

    for (int s = 0; s < T_STEPS; ++s) {
        float acc[8];
        if (!USE_XG) {
            float4 x4 = *(const float4*)(X + (size_t)s * KIN + kc * 4);
#pragma unroll
            for (int m = 0; m < 8; ++m) {
                float a = wih[m][0] * x4.x;
                a = fmaf(wih[m][1], x4.y, a);
                a = fmaf(wih[m][2], x4.z, a);
                a = fmaf(wih[m][3], x4.w, a);
                acc[m] = a;
            }
        } else {
#pragma unroll
            for (int m = 0; m < 8; ++m) acc[m] = 0.f;
        }

        // poll my 16 tagged h words for step s (parity buffer s&1).
        // tag semantics: word holds (h_bits<<32)|tag; tag==s means h_s.
        const unsigned long long* hp = hcom + (size_t)(s & 1) * HID;
        unsigned long long v[16];
        int guard = 1 << 20;
        for (;;) {
#pragma unroll
            for (int g = 0; g < 16; ++g)
                v[g] = __hip_atomic_load(hp + g * 128 + kc, __ATOMIC_RELAXED,
                                         __HIP_MEMORY_SCOPE_AGENT);
            bool ok = true;
#pragma unroll
            for (int g = 0; g < 16; ++g)
                ok &= ((unsigned int)v[g] >= (unsigned int)s);
            if (ok || --guard <= 0) break;
            __builtin_amdgcn_s_sleep(2);
        }
        float hv[16];
#pragma unroll
        for (int g = 0; g < 16; ++g) hv[g] = u2f((unsigned int)(v[g] >> 32));

#pragma unroll
        for (int m = 0; m < 8; ++m) {
            float a = acc[m];
#pragma unroll
            for (int g = 0; g < 16; ++g) a = fmaf(whh[m][g], hv[g], a);
            acc[m] = a;
        }

        // LDS partial sums: part[row][kc], stride 132 (16B-aligned rows)
#pragma unroll
        for (int m = 0; m < 8; ++m)
            part[(rg * 8 + m) * 132 + kc] = acc[m];
        __syncthreads();

        if (t < 32) {
            const float4* p4 = (const float4*)(part + t * 132);
            float s0 = 0.f, s1 = 0.f, s2 = 0.f, s3 = 0.f;
#pragma unroll
            for (int i = 0; i < 32; ++i) {
                float4 pv = p4[i];
                s0 += pv.x; s1 += pv.y; s2 += pv.z; s3 += pv.w;
            }
            float xv = 0.f;
            if (USE_XG)
                xv = xg[(size_t)s * GATES + (t >> 3) * HID + j0 + (t & 7)];
            gsum[t] = brow + xv + ((s0 + s1) + (s2 + s3));
        }
        __syncthreads();

        if (t < 8) {
            const float ig = gsum[t];
            const float fg = gsum[8 + t];
            const float gg = gsum[16 + t];
            const float og = gsum[24 + t];
            const float i_s = 1.f / (1.f + __expf(-ig));
            const float f_s = 1.f / (1.f + __expf(-fg));
            const float g_t = tanhf(gg);
            const float o_s = 1.f / (1.f + __expf(-og));
            c_state = f_s * c_state + i_s * g_t;
            const float h = o_s * tanhf(c_state);
            const unsigned long long pk =
                ((unsigned long long)__float_as_uint(h) << 32) | (unsigned int)(s + 1);
            __hip_atomic_store(&hcom[(size_t)((s + 1) & 1) * HID + j0 + t], pk,
                               __ATOMIC_RELAXED, __HIP_MEMORY_SCOPE_AGENT);
        }
        // part[] reuse: writers pass sync#2 before writing step s+1; readers
        // finished before sync#2. gsum reuse: ordered by sync#1 of step s+1.
    }
}

// ---------------- out[0] = h_T . W_lin + b_lin ----------------
__global__ __launch_bounds__(256) void final_linear(const unsigned long long* __restrict__ hcom,
                                                    const float* __restrict__ Wlin,
                                                    const float* __restrict__ blin,
                                                    float* __restrict__ out) {
    __shared__ float red[4];
    const int t = threadIdx.x;
    float a = 0.f;
#pragma unroll
    for (int e = 0; e < 8; ++e) {
        const int idx = t * 8 + e;
        a = fmaf(Wlin[idx], u2f((unsigned int)(hcom[idx] >> 32)), a);
    }
#pragma unroll
    for (int m = 1; m < 64; m <<= 1) a += __shfl_xor(a, m, 64);
    if ((t & 63) == 0) red[t >> 6] = a;
    __syncthreads();
    if (t == 0) out[0] = red[0] + red[1] + red[2] + red[3] + blin[0];
}

extern "C" void kernel_launch(void* const* d_in, const int* in_sizes, int n_in,
                              void* d_out, int out_size, void* d_ws, size_t ws_size,
                              hipStream_t stream) {
    const float* X    = (const float*)d_in[0];
    const float* Wih  = (const float*)d_in[1];
    const float* Whh  = (const float*)d_in[2];
    const float* bih  = (const float*)d_in[3];
    const float* bhh  = (const float*)d_in[4];
    const float* Wlin = (const float*)d_in[5];
    const float* blin = (const float*)d_in[6];
    float* out = (float*)d_out;

    char* ws = (char*)d_ws;
    const bool big = ws_size >= XG_BYTES + HCOM_BYTES;

    if (big) {
        float* xg = (float*)ws;
        unsigned long long* hcom = (unsigned long long*)(ws + XG_BYTES);
        (void)hipMemsetAsync(hcom, 0, HCOM_BYTES, stream);
        gemm_xg<<<dim3(GATES / 64, T_STEPS / 64), 256, 0, stream>>>(X, Wih, bih, bhh, xg);
        lstm_rec<1><<<dim3(NWG), dim3(NTHR), 0, stream>>>(X, Wih, xg, Whh, bih, bhh, hcom);
        final_linear<<<1, 256, 0, stream>>>(hcom, Wlin, blin, out);   // h_T: parity 0, tag 4096
    } else {
        unsigned long long* hcom = (unsigned long long*)ws;
        (void)hipMemsetAsync(hcom, 0, HCOM_BYTES, stream);
        lstm_rec<0><<<dim3(NWG), dim3(NTHR), 0, stream>>>(X, Wih, nullptr, Whh, bih, bhh, hcom);
        final_linear<<<1, 256, 0, stream>>>(hcom, Wlin, blin, out);
    }
}

// Round 5
// 11995.145 us; speedup vs baseline: 7.9233x; 1.3864x over previous
//
#include <hip/hip_runtime.h>

// LSTM T=4096, I=512, H=2048, 4H=8192, O=1, fp32.
// R5: dedup'd polling (waves 0-1 only + LDS rebroadcast), no s_sleep,
// xg prefetch before poll, packed v_pk_fma_f32 dot, shuffle-based tail.
// h published as tagged u64 (fp32bits<<32 | step), parity double buffer.

#define T_STEPS 4096
#define HID     2048
#define GATES   8192
#define KIN     512
#define NWG     256
#define NTHR    512
#define XG_BYTES ((size_t)T_STEPS * GATES * 4)
#define HCOM_BYTES (2UL * HID * 8UL)

typedef float v2f __attribute__((ext_vector_type(2)));

__device__ __forceinline__ float u2f(unsigned int u) {
    union { unsigned int u; float f; } x; x.u = u; return x.f;
}

// ---------------- xg = X @ Wih^T + (bih+bhh), fp32 tiled ----------------
__global__ __launch_bounds__(256) void gemm_xg(const float* __restrict__ A,
                                               const float* __restrict__ B,
                                               const float* __restrict__ bih,
                                               const float* __restrict__ bhh,
                                               float* __restrict__ C) {
    __shared__ float As[32][68];
    __shared__ float Bs[32][68];
    const int t  = threadIdx.x;
    const int tx = t & 15, ty = t >> 4;
    const int m0 = blockIdx.y * 64, n0 = blockIdx.x * 64;
    const int sr = t >> 3, sc = (t & 7) * 4;

    float c[4][4] = {};
    for (int k0 = 0; k0 < KIN; k0 += 32) {
        float4 a0 = *(const float4*)(A + (size_t)(m0 + sr)      * KIN + k0 + sc);
        float4 a1 = *(const float4*)(A + (size_t)(m0 + sr + 32) * KIN + k0 + sc);
        float4 b0 = *(const float4*)(B + (size_t)(n0 + sr)      * KIN + k0 + sc);
        float4 b1 = *(const float4*)(B + (size_t)(n0 + sr + 32) * KIN + k0 + sc);
        __syncthreads();
        As[sc+0][sr] = a0.x; As[sc+1][sr] = a0.y; As[sc+2][sr] = a0.z; As[sc+3][sr] = a0.w;
        As[sc+0][sr+32] = a1.x; As[sc+1][sr+32] = a1.y; As[sc+2][sr+32] = a1.z; As[sc+3][sr+32] = a1.w;
        Bs[sc+0][sr] = b0.x; Bs[sc+1][sr] = b0.y; Bs[sc+2][sr] = b0.z; Bs[sc+3][sr] = b0.w;
        Bs[sc+0][sr+32] = b1.x; Bs[sc+1][sr+32] = b1.y; Bs[sc+2][sr+32] = b1.z; Bs[sc+3][sr+32] = b1.w;
        __syncthreads();
#pragma unroll
        for (int kk = 0; kk < 32; ++kk) {
            float4 av = *(const float4*)&As[kk][ty * 4];
            float4 bv = *(const float4*)&Bs[kk][tx * 4];
            c[0][0] = fmaf(av.x, bv.x, c[0][0]); c[0][1] = fmaf(av.x, bv.y, c[0][1]);
            c[0][2] = fmaf(av.x, bv.z, c[0][2]); c[0][3] = fmaf(av.x, bv.w, c[0][3]);
            c[1][0] = fmaf(av.y, bv.x, c[1][0]); c[1][1] = fmaf(av.y, bv.y, c[1][1]);
            c[1][2] = fmaf(av.y, bv.z, c[1][2]); c[1][3] = fmaf(av.y, bv.w, c[1][3]);
            c[2][0] = fmaf(av.z, bv.x, c[2][0]); c[2][1] = fmaf(av.z, bv.y, c[2][1]);
            c[2][2] = fmaf(av.z, bv.z, c[2][2]); c[2][3] = fmaf(av.z, bv.w, c[2][3]);
            c[3][0] = fmaf(av.w, bv.x, c[3][0]); c[3][1] = fmaf(av.w, bv.y, c[3][1]);
            c[3][2] = fmaf(av.w, bv.z, c[3][2]); c[3][3] = fmaf(av.w, bv.w, c[3][3]);
        }
    }
    const int col = n0 + tx * 4;
    float4 bias;
    bias.x = bih[col]   + bhh[col];
    bias.y = bih[col+1] + bhh[col+1];
    bias.z = bih[col+2] + bhh[col+2];
    bias.w = bih[col+3] + bhh[col+3];
#pragma unroll
    for (int i = 0; i < 4; ++i) {
        float4 o;
        o.x = c[i][0] + bias.x; o.y = c[i][1] + bias.y;
        o.z = c[i][2] + bias.z; o.w = c[i][3] + bias.w;
        *(float4*)(C + (size_t)(m0 + ty * 4 + i) * GATES + col) = o;
    }
}

// ---------------- persistent recurrence ----------------
// 256 WGs x 512 thr. WG owns hidden [8b,8b+8) = 32 gate rows.
// kc=t&127 (k subset {g*128+kc}), rg=t>>7 gate group, 8 rows each.
template<int USE_XG>
__global__ __launch_bounds__(NTHR, 2) void lstm_rec(
    const float* __restrict__ X,
    const float* __restrict__ Wih,
    const float* __restrict__ xg,
    const float* __restrict__ Whh,
    const float* __restrict__ bih,
    const float* __restrict__ bhh,
    unsigned long long* __restrict__ hcom)
{
    const int t  = threadIdx.x;
    const int kc = t & 127;
    const int rg = t >> 7;
    const int j0 = blockIdx.x * 8;

    // register-resident W_hh slice, packed as float2 pairs over g
    v2f whh2[8][8];
#pragma unroll
    for (int m = 0; m < 8; ++m) {
        const float* wr = Whh + (size_t)(rg * HID + j0 + m) * HID + kc;
#pragma unroll
        for (int j = 0; j < 8; ++j) {
            v2f p; p.x = wr[(2 * j) * 128]; p.y = wr[(2 * j + 1) * 128];
            whh2[m][j] = p;
        }
    }
    float wih[8][4];
    if (!USE_XG) {
#pragma unroll
        for (int m = 0; m < 8; ++m) {
            float4 vx = *(const float4*)(Wih + (size_t)(rg * HID + j0 + m) * KIN + kc * 4);
            wih[m][0] = vx.x; wih[m][1] = vx.y; wih[m][2] = vx.z; wih[m][3] = vx.w;
        }
    }

    float brow = 0.f;
    if (t < 32) {
        const int grow = (t >> 3) * HID + j0 + (t & 7);
        brow = bih[grow] + bhh[grow];
    }

    __shared__ float hshare[HID];
    __shared__ float part[32 * 132];
    float c_state = 0.f;

    for (int s = 0; s < T_STEPS; ++s) {
        // prefetch xg (reducer rows) before the poll — hides HBM/LLC latency
        float xgv = 0.f;
        if (USE_XG && t < 32)
            xgv = xg[(size_t)s * GATES + (t >> 3) * HID + j0 + (t & 7)];

        v2f hv2[8];
        if (t < 128) {
            // waves 0-1 poll their 16 tagged words (parity s&1), no sleep
            const unsigned long long* hp = hcom + (size_t)(s & 1) * HID;
            unsigned long long v[16];
            int guard = 1 << 18;
            for (;;) {
#pragma unroll
                for (int g = 0; g < 16; ++g)
                    v[g] = __hip_atomic_load(hp + g * 128 + kc, __ATOMIC_RELAXED,
                                             __HIP_MEMORY_SCOPE_AGENT);
                bool ok = true;
#pragma unroll
                for (int g = 0; g < 16; ++g)
                    ok &= ((unsigned int)v[g] >= (unsigned int)s);
                if (ok || --guard <= 0) break;
            }
#pragma unroll
            for (int j = 0; j < 8; ++j) {
                v2f p;
                p.x = u2f((unsigned int)(v[2 * j] >> 32));
                p.y = u2f((unsigned int)(v[2 * j + 1] >> 32));
                hv2[j] = p;
                hshare[(2 * j) * 128 + kc]     = p.x;
                hshare[(2 * j + 1) * 128 + kc] = p.y;
            }
        }
        __syncthreads();                     // B1: hshare ready
        if (t >= 128) {
#pragma unroll
            for (int j = 0; j < 8; ++j) {
                v2f p;
                p.x = hshare[(2 * j) * 128 + kc];
                p.y = hshare[(2 * j + 1) * 128 + kc];
                hv2[j] = p;
            }
        }

        v2f acc2[8];
        if (!USE_XG) {
            float4 x4 = *(const float4*)(X + (size_t)s * KIN + kc * 4);
#pragma unroll
            for (int m = 0; m < 8; ++m) {
                float a = wih[m][0] * x4.x;
                a = fmaf(wih[m][1], x4.y, a);
                a = fmaf(wih[m][2], x4.z, a);
                a = fmaf(wih[m][3], x4.w, a);
                v2f z; z.x = a; z.y = 0.f; acc2[m] = z;
            }
        } else {
#pragma unroll
            for (int m = 0; m < 8; ++m) { v2f z; z.x = 0.f; z.y = 0.f; acc2[m] = z; }
        }

        // packed dot: v_pk_fma_f32, 64 packed FMAs per thread
#pragma unroll
        for (int m = 0; m < 8; ++m) {
            v2f a = acc2[m];
#pragma unroll
            for (int j = 0; j < 8; ++j)
                a = __builtin_elementwise_fma(whh2[m][j], hv2[j], a);
            acc2[m] = a;
        }
#pragma unroll
        for (int m = 0; m < 8; ++m)
            part[(rg * 8 + m) * 132 + kc] = acc2[m].x + acc2[m].y;
        __syncthreads();                     // B2: partials ready

        // tail: 64 threads reduce (2 per row), shuffle combine, 8 threads gate
        if (t < 64) {
            const int row = t & 31, half = t >> 5;
            const float4* p4 = (const float4*)(part + row * 132 + half * 64);
            float s0 = 0.f, s1 = 0.f, s2 = 0.f, s3 = 0.f;
#pragma unroll
            for (int i = 0; i < 16; ++i) {
                float4 pv = p4[i];
                s0 += pv.x; s1 += pv.y; s2 += pv.z; s3 += pv.w;
            }
            float sum = (s0 + s1) + (s2 + s3);
            sum += __shfl_xor(sum, 32, 64);  // combine the two halves
            sum += brow + xgv;               // valid on t<32 (rows)
            const float a1 = __shfl_down(sum, 8, 64);
            const float a2 = __shfl_down(sum, 16, 64);
            const float a3 = __shfl_down(sum, 24, 64);
            if (t < 8) {
                const float i_s = 1.f / (1.f + expf(-sum));   // gate i (row t)
                const float f_s = 1.f / (1.f + expf(-a1));    // gate f (row 8+t)
                const float g_t = tanhf(a2);                  // gate g (row 16+t)
                const float o_s = 1.f / (1.f + expf(-a3));    // gate o (row 24+t)
                c_state = f_s * c_state + i_s * g_t;
                const float h = o_s * tanhf(c_state);
                const unsigned long long pk =
                    ((unsigned long long)__float_as_uint(h) << 32) | (unsigned int)(s + 1);
                __hip_atomic_store(&hcom[(size_t)((s + 1) & 1) * HID + j0 + t], pk,
                                   __ATOMIC_RELAXED, __HIP_MEMORY_SCOPE_AGENT);
            }
        }
        // reuse safety: part(s+1)/hshare(s+1) writes are gated by poll(s+1),
        // which requires OWN publish(s+1), which happens after all reads of
        // part(s); hshare(s) reads precede B2(s).  (See R4 analysis.)
    }
}

// ---------------- out[0] = h_T . W_lin + b_lin ----------------
__global__ __launch_bounds__(256) void final_linear(const unsigned long long* __restrict__ hcom,
                                                    const float* __restrict__ Wlin,
                                                    const float* __restrict__ blin,
                                                    float* __restrict__ out) {
    __shared__ float red[4];
    const int t = threadIdx.x;
    float a = 0.f;
#pragma unroll
    for (int e = 0; e < 8; ++e) {
        const int idx = t * 8 + e;
        a = fmaf(Wlin[idx], u2f((unsigned int)(hcom[idx] >> 32)), a);
    }
#pragma unroll
    for (int m = 1; m < 64; m <<= 1) a += __shfl_xor(a, m, 64);
    if ((t & 63) == 0) red[t >> 6] = a;
    __syncthreads();
    if (t == 0) out[0] = red[0] + red[1] + red[2] + red[3] + blin[0];
}

extern "C" void kernel_launch(void* const* d_in, const int* in_sizes, int n_in,
                              void* d_out, int out_size, void* d_ws, size_t ws_size,
                              hipStream_t stream) {
    const float* X    = (const float*)d_in[0];
    const float* Wih  = (const float*)d_in[1];
    const float* Whh  = (const float*)d_in[2];
    const float* bih  = (const float*)d_in[3];
    const float* bhh  = (const float*)d_in[4];
    const float* Wlin = (const float*)d_in[5];
    const float* blin = (const float*)d_in[6];
    float* out = (float*)d_out;

    char* ws = (char*)d_ws;
    const bool big = ws_size >= XG_BYTES + HCOM_BYTES;

    if (big) {
        float* xg = (float*)ws;
        unsigned long long* hcom = (unsigned long long*)(ws + XG_BYTES);
        (void)hipMemsetAsync(hcom, 0, HCOM_BYTES, stream);
        gemm_xg<<<dim3(GATES / 64, T_STEPS / 64), 256, 0, stream>>>(X, Wih, bih, bhh, xg);
        lstm_rec<1><<<dim3(NWG), dim3(NTHR), 0, stream>>>(X, Wih, xg, Whh, bih, bhh, hcom);
        final_linear<<<1, 256, 0, stream>>>(hcom, Wlin, blin, out);
    } else {
        unsigned long long* hcom = (unsigned long long*)ws;
        (void)hipMemsetAsync(hcom, 0, HCOM_BYTES, stream);
        lstm_rec<0><<<dim3(NWG), dim3(NTHR), 0, stream>>>(X, Wih, nullptr, Whh, bih, bhh, hcom);
        final_linear<<<1, 256, 0, stream>>>(hcom, Wlin, blin, out);
    }
}